// Round 5
// baseline (251.947 us; speedup 1.0000x reference)
//
#include <hip/hip_runtime.h>

// Round 5: barrier-free register-direct MFMA. All A/B fragments load straight
// from global (L2-resident) into VGPRs; LDS used only for the per-wave P
// bounce (no sync needed) and the 2-barrier O-combine epilogue. K frags
// double-buffered in registers; V issued early each step.

typedef __bf16 bf16;
typedef __bf16 bf16x4 __attribute__((ext_vector_type(4)));
typedef __bf16 bf16x8 __attribute__((ext_vector_type(8)));
typedef float  f32x16 __attribute__((ext_vector_type(16)));

#define MFMA(a, b, c) __builtin_amdgcn_mfma_f32_32x32x16_bf16(a, b, c, 0, 0, 0)

constexpr int T = 4096, D = 1024, HS = 64;
constexpr int ROWS = 4 * T;                   // 16384
constexpr float QSCL = 0.045084220027797f;    // (1/32) * log2(e)

__device__ inline f32x16 zero16() {
    f32x16 z;
#pragma unroll
    for (int i = 0; i < 16; ++i) z[i] = 0.f;
    return z;
}

// ---- prep: Wt[192][1024] bf16 = concat(Wq^T*QSCL, Wk^T, Wv^T) ----
__global__ __launch_bounds__(256) void prep_wt(
    const float* __restrict__ Wq, const float* __restrict__ Wk,
    const float* __restrict__ Wv, bf16* __restrict__ Wt)
{
    __shared__ float Xf[64 * 68];
    const int m = blockIdx.x >> 4, dt = blockIdx.x & 15;
    const float* W = (m == 0) ? Wq : ((m == 1) ? Wk : Wv);
    const int d0 = dt * 64;
#pragma unroll
    for (int j = 0; j < 4; ++j) {
        int i = threadIdx.x + 256 * j;
        int dr = i >> 4, c4 = i & 15;
        float4 v = *(const float4*)(W + (size_t)(d0 + dr) * 64 + c4 * 4);
        *(float4*)&Xf[dr * 68 + c4 * 4] = v;
    }
    __syncthreads();
    const float scl = (m == 0) ? QSCL : 1.0f;
#pragma unroll
    for (int j = 0; j < 4; ++j) {
        int o = threadIdx.x + 256 * j;
        int h = o >> 4, dc = o & 15;
        bf16x4 w;
#pragma unroll
        for (int k = 0; k < 4; ++k) w[k] = (bf16)(Xf[(dc * 4 + k) * 68 + h] * scl);
        *(bf16x4*)(Wt + (size_t)(m * 64 + h) * D + d0 + dc * 4) = w;
    }
}

// ---- projection: barrier-free, register-direct. 256 blocks x 4 waves.
// Wave (hp, tt): acc0/acc1 = Q|K C^T-tiles (A = Wt rows, B = x frags),
// acc2 = V C-tile (A = x frags, B = Wt rows). x frags: fp32 loads + in-reg cvt.
__global__ __launch_bounds__(256, 2) void qkv_proj(
    const float* __restrict__ x, const bf16* __restrict__ Wt,
    bf16* __restrict__ Qg, bf16* __restrict__ Kg, bf16* __restrict__ Vtg)
{
    const int tid = threadIdx.x;
    const int w = tid >> 6, lane = tid & 63, ln5 = lane & 31, hi = lane >> 5;
    const int hp = w >> 1, tt = w & 1;
    const int r0 = blockIdx.x * 64;
    const int trow = r0 + tt * 32 + ln5;

    const float* xp  = x + (size_t)trow * D + hi * 8;
    const bf16* wqk0 = Wt + (size_t)(hp * 64 + ln5) * D + hi * 8;
    const bf16* wqk1 = Wt + (size_t)(hp * 64 + 32 + ln5) * D + hi * 8;
    const bf16* wvp  = Wt + (size_t)(128 + hp * 32 + ln5) * D + hi * 8;

    f32x16 acc0 = zero16(), acc1 = zero16(), acc2 = zero16();

    float4 xa[2][8];
#pragma unroll
    for (int ks = 0; ks < 4; ++ks) {
        xa[0][2 * ks]     = *(const float4*)(xp + ks * 16);
        xa[0][2 * ks + 1] = *(const float4*)(xp + ks * 16 + 4);
    }

    for (int kc = 0; kc < 16; ++kc) {
        const int cur = kc & 1, nxt = cur ^ 1;
        if (kc < 15) {
#pragma unroll
            for (int ks = 0; ks < 4; ++ks) {
                xa[nxt][2 * ks]     = *(const float4*)(xp + (kc + 1) * 64 + ks * 16);
                xa[nxt][2 * ks + 1] = *(const float4*)(xp + (kc + 1) * 64 + ks * 16 + 4);
            }
        }
        bf16x8 fx[4];
#pragma unroll
        for (int ks = 0; ks < 4; ++ks) {
            float4 a = xa[cur][2 * ks], b = xa[cur][2 * ks + 1];
            bf16x8 f;
            f[0] = (bf16)a.x; f[1] = (bf16)a.y; f[2] = (bf16)a.z; f[3] = (bf16)a.w;
            f[4] = (bf16)b.x; f[5] = (bf16)b.y; f[6] = (bf16)b.z; f[7] = (bf16)b.w;
            fx[ks] = f;
        }
#pragma unroll
        for (int ks = 0; ks < 4; ++ks) {
            bf16x8 a0 = *(const bf16x8*)(wqk0 + kc * 64 + ks * 16);
            bf16x8 a1 = *(const bf16x8*)(wqk1 + kc * 64 + ks * 16);
            bf16x8 bv = *(const bf16x8*)(wvp  + kc * 64 + ks * 16);
            acc0 = MFMA(a0, fx[ks], acc0);
            acc1 = MFMA(a1, fx[ks], acc1);
            acc2 = MFMA(fx[ks], bv, acc2);
        }
    }

    // Q/K: C^T (col=t=ln5, rows=h). V: C (col=h=ln5, rows=t).
    {
        int t = trow;
        f32x16 accs[2] = {acc0, acc1};
#pragma unroll
        for (int j = 0; j < 2; ++j) {
            int htile = 2 * hp + j;
            bf16* Og = (htile < 2) ? Qg : Kg;
            int hb = (htile & 1) * 32;
#pragma unroll
            for (int g = 0; g < 4; ++g) {
                bf16x4 vv;
#pragma unroll
                for (int k = 0; k < 4; ++k) vv[k] = (bf16)accs[j][4 * g + k];
                *(bf16x4*)(Og + (size_t)t * HS + hb + 8 * g + 4 * hi) = vv;
            }
        }
        int h = hp * 32 + ln5;
#pragma unroll
        for (int g = 0; g < 4; ++g) {
            bf16x4 vv;
#pragma unroll
            for (int k = 0; k < 4; ++k) vv[k] = (bf16)acc2[4 * g + k];
            *(bf16x4*)(Vtg + (size_t)h * ROWS + r0 + tt * 32 + 8 * g + 4 * hi) = vv;
        }
    }
}

// ---- attention: barrier-free k-loop, register-direct frags ----
// Wave (wq, wk): q-cols qt*64+wq*32, k-range (half*2+wk)*ns*64, ns steps of
// 64 krows. P bounce through per-wave LDS (no sync). 2-barrier epilogue.
__global__ __launch_bounds__(256, 2) void attn(
    const bf16* __restrict__ Qg, const bf16* __restrict__ Kg,
    const bf16* __restrict__ Vtg, float* __restrict__ Op,
    float* __restrict__ Lp, float* __restrict__ out, int split)
{
    __shared__ __align__(16) short Ps[4][32 * 72];   // per-wave, no sync needed
    __shared__ float Ox[64 * 64];
    __shared__ float Lx[2 * 64];

    const int tid = threadIdx.x;
    const int w = tid >> 6, lane = tid & 63, ln5 = lane & 31, hi = lane >> 5;
    const int wq = w & 1, wk = w >> 1;
    const int half = (split == 2) ? (blockIdx.x >> 8) : 0;
    const int r = blockIdx.x & 255;
    const int b = r & 3, qt = r >> 2;
    const int rbase = b * T;
    const int ns = (split == 2) ? 16 : 32;
    const int kb0 = rbase + (half * 2 + wk) * (ns * 64);

    // Q B-frags direct from global (constant over k-loop)
    const bf16* qp = Qg + (size_t)(rbase + qt * 64 + wq * 32 + ln5) * HS + hi * 8;
    bf16x8 bq[4];
#pragma unroll
    for (int ks = 0; ks < 4; ++ks) bq[ks] = *(const bf16x8*)(qp + ks * 16);

    const bf16* kp = Kg + (size_t)(kb0 + ln5) * HS + hi * 8;
    const bf16* vp = Vtg + (size_t)ln5 * ROWS + kb0 + hi * 8;

    f32x16 O0 = zero16(), O1 = zero16();
    float l = 0.f;
    short* Pw = &Ps[w][0];

    bf16x8 ka[2][2][4];
    auto loadK = [&](int buf, int i) {
#pragma unroll
        for (int h = 0; h < 2; ++h)
#pragma unroll
            for (int ks = 0; ks < 4; ++ks)
                ka[buf][h][ks] = *(const bf16x8*)(kp + (size_t)(i * 64 + h * 32) * HS + ks * 16);
    };
    loadK(0, 0);

    for (int i = 0; i < ns; ++i) {
        const int cur = i & 1;
        // V A-frags for this step (consumed late -> latency covered)
        bf16x8 va[2][4];
#pragma unroll
        for (int dv = 0; dv < 2; ++dv)
#pragma unroll
            for (int ks = 0; ks < 4; ++ks)
                va[dv][ks] = *(const bf16x8*)(vp + (size_t)(dv * 32) * ROWS + i * 64 + ks * 16);

        // S^T = K * Q^T
        f32x16 S0 = zero16(), S1 = zero16();
#pragma unroll
        for (int ks = 0; ks < 4; ++ks) {
            S0 = MFMA(ka[cur][0][ks], bq[ks], S0);
            S1 = MFMA(ka[cur][1][ks], bq[ks], S1);
        }
        if (i < ns - 1) loadK(cur ^ 1, i + 1);   // register prefetch next K

        // no-max softmax; write P^T (bf16) to per-wave LDS
#pragma unroll
        for (int g = 0; g < 4; ++g) {
            float p0 = __builtin_amdgcn_exp2f(S0[4 * g + 0]);
            float p1 = __builtin_amdgcn_exp2f(S0[4 * g + 1]);
            float p2 = __builtin_amdgcn_exp2f(S0[4 * g + 2]);
            float p3 = __builtin_amdgcn_exp2f(S0[4 * g + 3]);
            l += (p0 + p1) + (p2 + p3);
            bf16x4 pv; pv[0] = (bf16)p0; pv[1] = (bf16)p1; pv[2] = (bf16)p2; pv[3] = (bf16)p3;
            *(bf16x4*)&Pw[ln5 * 72 + 8 * g + 4 * hi] = pv;
        }
#pragma unroll
        for (int g = 0; g < 4; ++g) {
            float p0 = __builtin_amdgcn_exp2f(S1[4 * g + 0]);
            float p1 = __builtin_amdgcn_exp2f(S1[4 * g + 1]);
            float p2 = __builtin_amdgcn_exp2f(S1[4 * g + 2]);
            float p3 = __builtin_amdgcn_exp2f(S1[4 * g + 3]);
            l += (p0 + p1) + (p2 + p3);
            bf16x4 pv; pv[0] = (bf16)p0; pv[1] = (bf16)p1; pv[2] = (bf16)p2; pv[3] = (bf16)p3;
            *(bf16x4*)&Pw[ln5 * 72 + 32 + 8 * g + 4 * hi] = pv;
        }

        // O^T += V^T * P^T
#pragma unroll
        for (int ks = 0; ks < 4; ++ks) {
            bf16x8 bp = *(const bf16x8*)&Pw[ln5 * 72 + ks * 16 + hi * 8];
            O0 = MFMA(va[0][ks], bp, O0);
            O1 = MFMA(va[1][ks], bp, O1);
        }
    }

    l += __shfl_xor(l, 32, 64);                  // combine hi-halves per q-col

    // wk-combine epilogue (dedicated LDS, 1 barrier)
    if (wk == 1) {
#pragma unroll
        for (int rr = 0; rr < 16; ++rr) Ox[(wq * 32 + rr) * 64 + lane] = O0[rr];
#pragma unroll
        for (int rr = 0; rr < 16; ++rr) Ox[(wq * 32 + 16 + rr) * 64 + lane] = O1[rr];
        Lx[wq * 64 + lane] = l;
    }
    __syncthreads();
    if (wk == 0) {
#pragma unroll
        for (int rr = 0; rr < 16; ++rr) O0[rr] += Ox[(wq * 32 + rr) * 64 + lane];
#pragma unroll
        for (int rr = 0; rr < 16; ++rr) O1[rr] += Ox[(wq * 32 + 16 + rr) * 64 + lane];
        l += Lx[wq * 64 + lane];
        int qrow = rbase + qt * 64 + wq * 32 + ln5;
        if (split == 1) {
            float inv = 1.0f / l;
#pragma unroll
            for (int g = 0; g < 4; ++g) {
                float4 o;
                o.x = O0[4 * g + 0] * inv; o.y = O0[4 * g + 1] * inv;
                o.z = O0[4 * g + 2] * inv; o.w = O0[4 * g + 3] * inv;
                *(float4*)(out + (size_t)qrow * HS + 8 * g + 4 * hi) = o;
            }
#pragma unroll
            for (int g = 0; g < 4; ++g) {
                float4 o;
                o.x = O1[4 * g + 0] * inv; o.y = O1[4 * g + 1] * inv;
                o.z = O1[4 * g + 2] * inv; o.w = O1[4 * g + 3] * inv;
                *(float4*)(out + (size_t)qrow * HS + 32 + 8 * g + 4 * hi) = o;
            }
        } else {
            float* Od = Op + (size_t)half * ROWS * HS + (size_t)qrow * HS;
#pragma unroll
            for (int g = 0; g < 4; ++g) {
                float4 o;
                o.x = O0[4 * g + 0]; o.y = O0[4 * g + 1];
                o.z = O0[4 * g + 2]; o.w = O0[4 * g + 3];
                *(float4*)(Od + 8 * g + 4 * hi) = o;
            }
#pragma unroll
            for (int g = 0; g < 4; ++g) {
                float4 o;
                o.x = O1[4 * g + 0]; o.y = O1[4 * g + 1];
                o.z = O1[4 * g + 2]; o.w = O1[4 * g + 3];
                *(float4*)(Od + 32 + 8 * g + 4 * hi) = o;
            }
            if (hi == 0) Lp[half * ROWS + qrow] = l;
        }
    }
}

// ---- reduce: out = (O0 + O1) / (l0 + l1) ----
__global__ __launch_bounds__(256) void attn_reduce(
    const float* __restrict__ Op, const float* __restrict__ Lp,
    float* __restrict__ out)
{
    int idx = blockIdx.x * 256 + threadIdx.x;        // float4 index
    int row = idx >> 4;
    float4 a = *(const float4*)(Op + (size_t)idx * 4);
    float4 b = *(const float4*)(Op + (size_t)ROWS * HS + (size_t)idx * 4);
    float inv = 1.0f / (Lp[row] + Lp[ROWS + row]);
    float4 o;
    o.x = (a.x + b.x) * inv; o.y = (a.y + b.y) * inv;
    o.z = (a.z + b.z) * inv; o.w = (a.w + b.w) * inv;
    *(float4*)(out + (size_t)idx * 4) = o;
}

extern "C" void kernel_launch(void* const* d_in, const int* in_sizes, int n_in,
                              void* d_out, int out_size, void* d_ws, size_t ws_size,
                              hipStream_t stream)
{
    const float* x  = (const float*)d_in[0];
    const float* Wq = (const float*)d_in[1];
    const float* Wk = (const float*)d_in[2];
    const float* Wv = (const float*)d_in[3];
    float* out = (float*)d_out;

    char* ws = (char*)d_ws;
    bf16* Qg  = (bf16*)(ws);                          // 2 MB  [16384][64]
    bf16* Kg  = (bf16*)(ws + ((size_t)2 << 20));      // 2 MB  [16384][64]
    bf16* Vtg = (bf16*)(ws + ((size_t)4 << 20));      // 2 MB  [64][16384]
    bf16* Wt  = (bf16*)(ws + ((size_t)6 << 20));      // 384 KB [192][1024]
    float* Lp = (float*)(ws + ((size_t)6 << 20));     // overlays Wt (dead after proj)
    float* Op = (float*)(ws + ((size_t)6 << 20) + ((size_t)1 << 19));

    size_t need = ((size_t)6 << 20) + ((size_t)1 << 19)
                + (size_t)2 * ROWS * HS * sizeof(float);
    int split = (ws_size >= need) ? 2 : 1;

    prep_wt<<<48, 256, 0, stream>>>(Wq, Wk, Wv, Wt);
    qkv_proj<<<ROWS / 64, 256, 0, stream>>>(x, Wt, Qg, Kg, Vtg);
    attn<<<256 * split, 256, 0, stream>>>(Qg, Kg, Vtg, Op, Lp, out, split);
    if (split == 2)
        attn_reduce<<<(ROWS * HS / 4) / 256, 256, 0, stream>>>(Op, Lp, out);
}

// Round 6
// 233.597 us; speedup vs baseline: 1.0786x; 1.0786x over previous
//
#include <hip/hip_runtime.h>

// Round 6: fully barrier-free, spill-free register-direct MFMA.
//  - attn: one wave = 32 q-cols, full k-segment, JIT K/V frag loads (no reg
//    double-buffer -> no spill; R5's 260MB scratch writes were the ka buffer).
//    No inter-wave combine, zero __syncthreads. k-split=4 across blocks.
//  - proj: 3 blocks per 64-row tile (Q/K/V), 1 MFMA tile per wave, grid 768.
//  - XCD swizzles keep L2-sharing blocks on the same XCD.

typedef __bf16 bf16;
typedef __bf16 bf16x4 __attribute__((ext_vector_type(4)));
typedef __bf16 bf16x8 __attribute__((ext_vector_type(8)));
typedef float  f32x16 __attribute__((ext_vector_type(16)));

#define MFMA(a, b, c) __builtin_amdgcn_mfma_f32_32x32x16_bf16(a, b, c, 0, 0, 0)

constexpr int T = 4096, D = 1024, HS = 64;
constexpr int ROWS = 4 * T;                   // 16384
constexpr float QSCL = 0.045084220027797f;    // (1/32) * log2(e)

__device__ inline f32x16 zero16() {
    f32x16 z;
#pragma unroll
    for (int i = 0; i < 16; ++i) z[i] = 0.f;
    return z;
}

// ---- prep: Wt[192][1024] bf16 = concat(Wq^T*QSCL, Wk^T, Wv^T) ----
__global__ __launch_bounds__(256) void prep_wt(
    const float* __restrict__ Wq, const float* __restrict__ Wk,
    const float* __restrict__ Wv, bf16* __restrict__ Wt)
{
    __shared__ float Xf[64 * 68];
    const int m = blockIdx.x >> 4, dt = blockIdx.x & 15;
    const float* W = (m == 0) ? Wq : ((m == 1) ? Wk : Wv);
    const int d0 = dt * 64;
#pragma unroll
    for (int j = 0; j < 4; ++j) {
        int i = threadIdx.x + 256 * j;
        int dr = i >> 4, c4 = i & 15;
        float4 v = *(const float4*)(W + (size_t)(d0 + dr) * 64 + c4 * 4);
        *(float4*)&Xf[dr * 68 + c4 * 4] = v;
    }
    __syncthreads();
    const float scl = (m == 0) ? QSCL : 1.0f;
#pragma unroll
    for (int j = 0; j < 4; ++j) {
        int o = threadIdx.x + 256 * j;
        int h = o >> 4, dc = o & 15;
        bf16x4 w;
#pragma unroll
        for (int k = 0; k < 4; ++k) w[k] = (bf16)(Xf[(dc * 4 + k) * 68 + h] * scl);
        *(bf16x4*)(Wt + (size_t)(m * 64 + h) * D + d0 + dc * 4) = w;
    }
}

// ---- projection: grid 768 = 8 xcd x 32 mlocal x 3 which (Q/K/V).
// Wave (tt = t-half, hh = h-half) computes one 32x32 tile over full K=1024.
// x double-buffered one kc ahead; W frags from L2. No LDS, no barriers.
__global__ __launch_bounds__(256, 2) void qkv_proj(
    const float* __restrict__ x, const bf16* __restrict__ Wt,
    bf16* __restrict__ Qg, bf16* __restrict__ Kg, bf16* __restrict__ Vtg)
{
    const int tid = threadIdx.x;
    const int w = tid >> 6, lane = tid & 63, ln5 = lane & 31, hi = lane >> 5;
    const int tt = w & 1, hh = w >> 1;
    const int xcd = blockIdx.x & 7, t3 = blockIdx.x >> 3;
    const int which = t3 % 3, mlocal = t3 / 3;       // same-row blocks share xcd
    const int r0 = (xcd * 32 + mlocal) * 64;
    const int trow = r0 + tt * 32 + ln5;

    const float* xp = x + (size_t)trow * D + hi * 8;
    const bf16*  wp = Wt + (size_t)(which * 64 + hh * 32 + ln5) * D + hi * 8;

    f32x16 acc = zero16();
    float4 xa[2][8];
#pragma unroll
    for (int ks = 0; ks < 4; ++ks) {
        xa[0][2 * ks]     = *(const float4*)(xp + ks * 16);
        xa[0][2 * ks + 1] = *(const float4*)(xp + ks * 16 + 4);
    }

    for (int kc = 0; kc < 16; ++kc) {
        const int cur = kc & 1, nxt = cur ^ 1;
        if (kc < 15) {
#pragma unroll
            for (int ks = 0; ks < 4; ++ks) {
                xa[nxt][2 * ks]     = *(const float4*)(xp + (kc + 1) * 64 + ks * 16);
                xa[nxt][2 * ks + 1] = *(const float4*)(xp + (kc + 1) * 64 + ks * 16 + 4);
            }
        }
#pragma unroll
        for (int ks = 0; ks < 4; ++ks) {
            float4 a = xa[cur][2 * ks], b = xa[cur][2 * ks + 1];
            bf16x8 fx;
            fx[0] = (bf16)a.x; fx[1] = (bf16)a.y; fx[2] = (bf16)a.z; fx[3] = (bf16)a.w;
            fx[4] = (bf16)b.x; fx[5] = (bf16)b.y; fx[6] = (bf16)b.z; fx[7] = (bf16)b.w;
            bf16x8 wf = *(const bf16x8*)(wp + kc * 64 + ks * 16);
            if (which < 2) acc = MFMA(wf, fx, acc);   // C^T = W x^T (col=t)
            else           acc = MFMA(fx, wf, acc);   // C   = x W^T (col=h)
        }
    }

    if (which < 2) {
        bf16* Og = (which == 0) ? Qg : Kg;
#pragma unroll
        for (int g = 0; g < 4; ++g) {
            bf16x4 v;
#pragma unroll
            for (int k = 0; k < 4; ++k) v[k] = (bf16)acc[4 * g + k];
            *(bf16x4*)(Og + (size_t)trow * HS + hh * 32 + 8 * g + 4 * hi) = v;
        }
    } else {
        int h = hh * 32 + ln5;
#pragma unroll
        for (int g = 0; g < 4; ++g) {
            bf16x4 v;
#pragma unroll
            for (int k = 0; k < 4; ++k) v[k] = (bf16)acc[4 * g + k];
            *(bf16x4*)(Vtg + (size_t)h * ROWS + r0 + tt * 32 + 8 * g + 4 * hi) = v;
        }
    }
}

// ---- attention: wave-independent, zero barriers. Wave = 32 q-cols,
// block = 128 q-rows (4 waves), k-segment of T/split rows, JIT frag loads.
__global__ __launch_bounds__(256, 2) void attn(
    const bf16* __restrict__ Qg, const bf16* __restrict__ Kg,
    const bf16* __restrict__ Vtg, float* __restrict__ Op,
    float* __restrict__ Lp, float* __restrict__ out, int split)
{
    __shared__ __align__(16) short Ps[4][32 * 72];   // per-wave P bounce

    const int tid = threadIdx.x;
    const int w = tid >> 6, lane = tid & 63, ln5 = lane & 31, hi = lane >> 5;

    int b, qt, half;
    if (split == 4) {       // xcd swizzle: (b,half) combo pinned to an XCD
        int xcd = blockIdx.x & 7, j = blockIdx.x >> 3;
        qt = j & 31;
        int combo = xcd + 8 * (j >> 5);
        b = combo >> 2; half = combo & 3;
    } else {
        half = blockIdx.x >> 7;
        int r = blockIdx.x & 127;
        b = r & 3; qt = r >> 2;
    }
    const int rbase = b * T;
    const int ns = (T / 64) / split;
    const int kb0 = rbase + half * (ns * 64);
    const int qrow = rbase + qt * 128 + w * 32 + ln5;

    const bf16* qp = Qg + (size_t)qrow * HS + hi * 8;
    bf16x8 bq[4];
#pragma unroll
    for (int ks = 0; ks < 4; ++ks) bq[ks] = *(const bf16x8*)(qp + ks * 16);

    const bf16* kp = Kg + (size_t)(kb0 + ln5) * HS + hi * 8;
    const bf16* vp = Vtg + (size_t)ln5 * ROWS + kb0 + hi * 8;

    f32x16 O0 = zero16(), O1 = zero16();
    float l = 0.f;
    short* Pw = &Ps[w][0];

    for (int i = 0; i < ns; ++i) {
        // S^T = K * Q^T  (JIT K frags; no persistent buffer)
        f32x16 S0 = zero16(), S1 = zero16();
#pragma unroll
        for (int ks = 0; ks < 4; ++ks) {
            bf16x8 a0 = *(const bf16x8*)(kp + (size_t)(i * 64)      * HS + ks * 16);
            bf16x8 a1 = *(const bf16x8*)(kp + (size_t)(i * 64 + 32) * HS + ks * 16);
            S0 = MFMA(a0, bq[ks], S0);
            S1 = MFMA(a1, bq[ks], S1);
        }

        // no-max softmax; P^T (bf16) to per-wave LDS
#pragma unroll
        for (int g = 0; g < 4; ++g) {
            float p0 = __builtin_amdgcn_exp2f(S0[4 * g + 0]);
            float p1 = __builtin_amdgcn_exp2f(S0[4 * g + 1]);
            float p2 = __builtin_amdgcn_exp2f(S0[4 * g + 2]);
            float p3 = __builtin_amdgcn_exp2f(S0[4 * g + 3]);
            l += (p0 + p1) + (p2 + p3);
            bf16x4 pv; pv[0] = (bf16)p0; pv[1] = (bf16)p1; pv[2] = (bf16)p2; pv[3] = (bf16)p3;
            *(bf16x4*)&Pw[ln5 * 72 + 8 * g + 4 * hi] = pv;
        }
#pragma unroll
        for (int g = 0; g < 4; ++g) {
            float p0 = __builtin_amdgcn_exp2f(S1[4 * g + 0]);
            float p1 = __builtin_amdgcn_exp2f(S1[4 * g + 1]);
            float p2 = __builtin_amdgcn_exp2f(S1[4 * g + 2]);
            float p3 = __builtin_amdgcn_exp2f(S1[4 * g + 3]);
            l += (p0 + p1) + (p2 + p3);
            bf16x4 pv; pv[0] = (bf16)p0; pv[1] = (bf16)p1; pv[2] = (bf16)p2; pv[3] = (bf16)p3;
            *(bf16x4*)&Pw[ln5 * 72 + 32 + 8 * g + 4 * hi] = pv;
        }

        // O^T += V^T * P^T  (JIT V frags)
#pragma unroll
        for (int ks = 0; ks < 4; ++ks) {
            bf16x8 bp = *(const bf16x8*)&Pw[ln5 * 72 + ks * 16 + hi * 8];
            bf16x8 v0 = *(const bf16x8*)(vp + i * 64 + ks * 16);
            bf16x8 v1 = *(const bf16x8*)(vp + (size_t)32 * ROWS + i * 64 + ks * 16);
            O0 = MFMA(v0, bp, O0);
            O1 = MFMA(v1, bp, O1);
        }
    }

    l += __shfl_xor(l, 32, 64);                  // hi-half rows of same q-col

    if (split == 1) {
        float inv = 1.0f / l;
#pragma unroll
        for (int g = 0; g < 4; ++g) {
            float4 o;
            o.x = O0[4 * g + 0] * inv; o.y = O0[4 * g + 1] * inv;
            o.z = O0[4 * g + 2] * inv; o.w = O0[4 * g + 3] * inv;
            *(float4*)(out + (size_t)qrow * HS + 8 * g + 4 * hi) = o;
        }
#pragma unroll
        for (int g = 0; g < 4; ++g) {
            float4 o;
            o.x = O1[4 * g + 0] * inv; o.y = O1[4 * g + 1] * inv;
            o.z = O1[4 * g + 2] * inv; o.w = O1[4 * g + 3] * inv;
            *(float4*)(out + (size_t)qrow * HS + 32 + 8 * g + 4 * hi) = o;
        }
    } else {
        float* Od = Op + (size_t)half * ROWS * HS + (size_t)qrow * HS;
#pragma unroll
        for (int g = 0; g < 4; ++g) {
            float4 o;
            o.x = O0[4 * g + 0]; o.y = O0[4 * g + 1];
            o.z = O0[4 * g + 2]; o.w = O0[4 * g + 3];
            *(float4*)(Od + 8 * g + 4 * hi) = o;
        }
#pragma unroll
        for (int g = 0; g < 4; ++g) {
            float4 o;
            o.x = O1[4 * g + 0]; o.y = O1[4 * g + 1];
            o.z = O1[4 * g + 2]; o.w = O1[4 * g + 3];
            *(float4*)(Od + 32 + 8 * g + 4 * hi) = o;
        }
        if (hi == 0) Lp[half * ROWS + qrow] = l;
    }
}

// ---- reduce: out = sum_h(O_h) / sum_h(l_h) ----
__global__ __launch_bounds__(256) void attn_reduce(
    const float* __restrict__ Op, const float* __restrict__ Lp,
    float* __restrict__ out, int split)
{
    int idx = blockIdx.x * 256 + threadIdx.x;        // float4 index
    int row = idx >> 4;
    float4 s; s.x = s.y = s.z = s.w = 0.f;
    float lsum = 0.f;
    for (int h = 0; h < split; ++h) {
        float4 a = *(const float4*)(Op + (size_t)h * ROWS * HS + (size_t)idx * 4);
        s.x += a.x; s.y += a.y; s.z += a.z; s.w += a.w;
        lsum += Lp[h * ROWS + row];
    }
    float inv = 1.0f / lsum;
    s.x *= inv; s.y *= inv; s.z *= inv; s.w *= inv;
    *(float4*)(out + (size_t)idx * 4) = s;
}

extern "C" void kernel_launch(void* const* d_in, const int* in_sizes, int n_in,
                              void* d_out, int out_size, void* d_ws, size_t ws_size,
                              hipStream_t stream)
{
    const float* x  = (const float*)d_in[0];
    const float* Wq = (const float*)d_in[1];
    const float* Wk = (const float*)d_in[2];
    const float* Wv = (const float*)d_in[3];
    float* out = (float*)d_out;

    char* ws = (char*)d_ws;
    bf16* Qg  = (bf16*)(ws);                          // 2 MB  [16384][64]
    bf16* Kg  = (bf16*)(ws + ((size_t)2 << 20));      // 2 MB  [16384][64]
    bf16* Vtg = (bf16*)(ws + ((size_t)4 << 20));      // 2 MB  [64][16384]
    bf16* Wt  = (bf16*)(ws + ((size_t)6 << 20));      // 384 KB [192][1024]
    float* Lp = (float*)(ws + ((size_t)6 << 20));     // overlays Wt (dead after proj)
    float* Op = (float*)(ws + ((size_t)6 << 20) + ((size_t)1 << 19));

    const size_t base = ((size_t)6 << 20) + ((size_t)1 << 19);
    int split = 1;
    if (ws_size >= base + (size_t)4 * ROWS * HS * sizeof(float)) split = 4;
    else if (ws_size >= base + (size_t)2 * ROWS * HS * sizeof(float)) split = 2;

    prep_wt<<<48, 256, 0, stream>>>(Wq, Wk, Wv, Wt);
    qkv_proj<<<768, 256, 0, stream>>>(x, Wt, Qg, Kg, Vtg);
    attn<<<128 * split, 256, 0, stream>>>(Qg, Kg, Vtg, Op, Lp, out, split);
    if (split > 1)
        attn_reduce<<<(ROWS * HS / 4) / 256, 256, 0, stream>>>(Op, Lp, out, split);
}

// Round 7
// 154.163 us; speedup vs baseline: 1.6343x; 1.5153x over previous
//
#include <hip/hip_runtime.h>

// Round 7: m97-style global_load_lds staging everywhere.
//  - Kgt/Vgt stored TILED (contiguous 8KB per 64-t-row tile) and bank-swizzled
//    in global memory by proj, so attn stages them with linear global_load_lds
//    (wave-uniform base + lane*16) and reads frags conflict-free (unit ^= row&7).
//  - attn: chunk=128 kr staged per block; R4-verified wave split (wq,wk),
//    per-wave P bounce, wk-combine epilogue; k-split across blocks, XCD-pinned.
//  - proj: M=64 x N=192 per block, x-tile (fp32) + Wt-chunk staged per kc.

typedef __bf16 bf16;
typedef __bf16 bf16x4 __attribute__((ext_vector_type(4)));
typedef __bf16 bf16x8 __attribute__((ext_vector_type(8)));
typedef float  f32x16 __attribute__((ext_vector_type(16)));

#define MFMA(a, b, c) __builtin_amdgcn_mfma_f32_32x32x16_bf16(a, b, c, 0, 0, 0)

constexpr int T = 4096, D = 1024, HS = 64;
constexpr int ROWS = 4 * T;                   // 16384
constexpr float QSCL = 0.045084220027797f;    // (1/32) * log2(e)

__device__ __forceinline__ void gld16(const void* g, void* l) {
    __builtin_amdgcn_global_load_lds(
        (const __attribute__((address_space(1))) unsigned int*)g,
        (__attribute__((address_space(3))) unsigned int*)l, 16, 0, 0);
}

__device__ inline f32x16 zero16() {
    f32x16 z;
#pragma unroll
    for (int i = 0; i < 16; ++i) z[i] = 0.f;
    return z;
}

// ---- prep: Wt[192][1024] bf16 = concat(Wq^T*QSCL, Wk^T, Wv^T) ----
__global__ __launch_bounds__(256) void prep_wt(
    const float* __restrict__ Wq, const float* __restrict__ Wk,
    const float* __restrict__ Wv, bf16* __restrict__ Wt)
{
    __shared__ float Xf[64 * 68];
    const int m = blockIdx.x >> 4, dt = blockIdx.x & 15;
    const float* W = (m == 0) ? Wq : ((m == 1) ? Wk : Wv);
    const int d0 = dt * 64;
#pragma unroll
    for (int j = 0; j < 4; ++j) {
        int i = threadIdx.x + 256 * j;
        int dr = i >> 4, c4 = i & 15;
        float4 v = *(const float4*)(W + (size_t)(d0 + dr) * 64 + c4 * 4);
        *(float4*)&Xf[dr * 68 + c4 * 4] = v;
    }
    __syncthreads();
    const float scl = (m == 0) ? QSCL : 1.0f;
#pragma unroll
    for (int j = 0; j < 4; ++j) {
        int o = threadIdx.x + 256 * j;
        int h = o >> 4, dc = o & 15;
        bf16x4 w;
#pragma unroll
        for (int k = 0; k < 4; ++k) w[k] = (bf16)(Xf[(dc * 4 + k) * 68 + h] * scl);
        *(bf16x4*)(Wt + (size_t)(m * 64 + h) * D + d0 + dc * 4) = w;
    }
}

// ---- projection: grid 256, block = 64 t-rows x all 192 cols, K-chunks of 64.
// Wave (tt,hh): Q,K (C^T = W x^T) + V (C = x W^T) 32x32 tiles, 12 MFMA/chunk.
__global__ __launch_bounds__(256, 1) void qkv_proj(
    const float* __restrict__ x, const bf16* __restrict__ Wt,
    bf16* __restrict__ Qg, bf16* __restrict__ Kgt, bf16* __restrict__ Vgt)
{
    __shared__ __align__(16) float Xs[64 * 64];    // [r][j]: x[r0+r][kc*64+(j^(r&15))*4..+4]
    __shared__ __align__(16) short Ws[192 * 64];   // [h][j]: Wt[h][kc*64+(j^(h&7))*8..+8]
    const int tid = threadIdx.x;
    const int w = tid >> 6, lane = tid & 63, ln5 = lane & 31, hi = lane >> 5;
    const int tt = w & 1, hh = w >> 1;
    const int r0 = blockIdx.x * 64;
    const int wb = tid & 448;                      // w*64 (wave-uniform)

    f32x16 accQ = zero16(), accK = zero16(), accV = zero16();
    const int rx  = tt * 32 + ln5;                 // x frag row
    const int hq  = hh * 32 + ln5;                 // Wt frag row (Q; +64 K; +128 V)
    const int swz = ln5 & 7;

    for (int kc = 0; kc < 16; ++kc) {
        __syncthreads();
#pragma unroll
        for (int k2 = 0; k2 < 4; ++k2) {           // x tile 16 KB
            int s = k2 * 256 + tid;
            int r = s >> 4, j = s & 15, u = j ^ (r & 15);
            gld16(x + (size_t)(r0 + r) * D + kc * 64 + u * 4,
                  &Xs[(k2 * 256 + wb) * 4]);
        }
#pragma unroll
        for (int k2 = 0; k2 < 6; ++k2) {           // Wt chunk 24 KB
            int s = k2 * 256 + tid;
            int h = s >> 3, j = s & 7, u = j ^ (h & 7);
            gld16(Wt + (size_t)h * D + kc * 64 + u * 8,
                  &Ws[(k2 * 256 + wb) * 8]);
        }
        __syncthreads();

        bf16x8 fx[4];
#pragma unroll
        for (int ks = 0; ks < 4; ++ks) {           // fp32 -> bf16 frags
            int u0 = ks * 4 + hi * 2;
            float4 a = *(const float4*)&Xs[rx * 64 + ((u0)     ^ (rx & 15)) * 4];
            float4 b = *(const float4*)&Xs[rx * 64 + ((u0 + 1) ^ (rx & 15)) * 4];
            bf16x8 f;
            f[0] = (bf16)a.x; f[1] = (bf16)a.y; f[2] = (bf16)a.z; f[3] = (bf16)a.w;
            f[4] = (bf16)b.x; f[5] = (bf16)b.y; f[6] = (bf16)b.z; f[7] = (bf16)b.w;
            fx[ks] = f;
        }
#pragma unroll
        for (int ks = 0; ks < 4; ++ks) {
            int j = ((ks * 2 + hi) ^ swz) * 8;
            bf16x8 aq = *(const bf16x8*)&Ws[(hq)       * 64 + j];
            bf16x8 ak = *(const bf16x8*)&Ws[(hq + 64)  * 64 + j];
            bf16x8 bv = *(const bf16x8*)&Ws[(hq + 128) * 64 + j];
            accQ = MFMA(aq, fx[ks], accQ);
            accK = MFMA(ak, fx[ks], accK);
            accV = MFMA(fx[ks], bv, accV);
        }
    }

    // epilogue: Q plain [t][h]; Kgt tiled+swizzled [t][j]; Vgt tiled+swizzled [tile][hr][j]
    {
        int t = r0 + tt * 32 + ln5;                // Q/K lane col = t
#pragma unroll
        for (int g = 0; g < 4; ++g) {
            int h0 = hh * 32 + 8 * g + 4 * hi;
            bf16x4 vq, vk;
#pragma unroll
            for (int k = 0; k < 4; ++k) { vq[k] = (bf16)accQ[4*g+k]; vk[k] = (bf16)accK[4*g+k]; }
            *(bf16x4*)(Qg + (size_t)t * HS + h0) = vq;
            int j = (h0 >> 3) ^ (t & 7);
            *(bf16x4*)(Kgt + (size_t)t * HS + j * 8 + 4 * hi) = vk;
        }
        int hr = hh * 32 + ln5;                    // V lane col = h
#pragma unroll
        for (int g = 0; g < 4; ++g) {
            int t0 = tt * 32 + 8 * g + 4 * hi;     // tile-local t
            bf16x4 vv;
#pragma unroll
            for (int k = 0; k < 4; ++k) vv[k] = (bf16)accV[4*g+k];
            int j = (t0 >> 3) ^ (hr & 7);
            *(bf16x4*)(Vgt + (size_t)blockIdx.x * 4096 + hr * 64 + j * 8 + 4 * hi) = vv;
        }
    }
}

// ---- attention: 64 q-rows/block, 128-kr chunks staged via global_load_lds ----
__global__ __launch_bounds__(256, 2) void attn(
    const bf16* __restrict__ Qg, const bf16* __restrict__ Kgt,
    const bf16* __restrict__ Vgt, float* __restrict__ Op,
    float* __restrict__ Lp, float* __restrict__ out, int split)
{
    __shared__ __align__(16) short KV[16384];      // K tiles [0,8192), V tiles [8192,16384)
    __shared__ __align__(16) short Ps[4][32 * 72]; // per-wave P bounce
    __shared__ float Lx[128];

    const int tid = threadIdx.x;
    const int w = tid >> 6, lane = tid & 63, ln5 = lane & 31, hi = lane >> 5;
    const int wq = w & 1, wk = w >> 1;
    const int wb = tid & 448;

    int b, qt, half;
    if (split == 2)      { int c2 = blockIdx.x & 7;  b = c2 >> 1; half = c2 & 1; qt = blockIdx.x >> 3; }
    else if (split == 4) { int c2 = blockIdx.x & 15; b = c2 >> 2; half = c2 & 3; qt = blockIdx.x >> 4; }
    else                 { b = blockIdx.x & 3; half = 0; qt = blockIdx.x >> 2; }
    const int rbase = b * T;
    const int seg = T / split;
    const int kb0 = rbase + half * seg;
    const int nc = seg / 128;
    const int qrow = rbase + qt * 64 + wq * 32 + ln5;

    const bf16* qp = Qg + (size_t)qrow * HS + hi * 8;
    bf16x8 bq[4];
#pragma unroll
    for (int ks = 0; ks < 4; ++ks) bq[ks] = *(const bf16x8*)(qp + ks * 16);

    f32x16 O0 = zero16(), O1 = zero16();
    float l = 0.f;
    short* Pw = &Ps[w][0];
    const int swz = ln5 & 7;
    const int krow0 = wk * 4096 + ln5 * 64;
    const int krow1 = wk * 4096 + (32 + ln5) * 64;
    const int vrow0 = 8192 + wk * 4096 + ln5 * 64;
    const int vrow1 = 8192 + wk * 4096 + (32 + ln5) * 64;
    const bf16* Kc = Kgt + (size_t)kb0 * HS;       // tiled flat: t*64
    const bf16* Vc = Vgt + (size_t)kb0 * HS;

    for (int c = 0; c < nc; ++c) {
        __syncthreads();                           // prev chunk reads done
#pragma unroll
        for (int k2 = 0; k2 < 4; ++k2) {           // 16 KB K + 16 KB V, linear
            int s = k2 * 256 + tid;
            gld16(Kc + (size_t)c * 8192 + s * 8, &KV[(k2 * 256 + wb) * 8]);
            gld16(Vc + (size_t)c * 8192 + s * 8, &KV[8192 + (k2 * 256 + wb) * 8]);
        }
        __syncthreads();                           // drain vmcnt -> data visible

        // S^T = K * Q^T  (wave's 64-kr tile = wk)
        f32x16 S0 = zero16(), S1 = zero16();
#pragma unroll
        for (int ks = 0; ks < 4; ++ks) {
            int j = ((ks * 2 + hi) ^ swz) * 8;
            bf16x8 a0 = *(const bf16x8*)&KV[krow0 + j];
            bf16x8 a1 = *(const bf16x8*)&KV[krow1 + j];
            S0 = MFMA(a0, bq[ks], S0);
            S1 = MFMA(a1, bq[ks], S1);
        }

        // no-max softmax; P^T (bf16) to per-wave LDS
#pragma unroll
        for (int g = 0; g < 4; ++g) {
            float p0 = __builtin_amdgcn_exp2f(S0[4 * g + 0]);
            float p1 = __builtin_amdgcn_exp2f(S0[4 * g + 1]);
            float p2 = __builtin_amdgcn_exp2f(S0[4 * g + 2]);
            float p3 = __builtin_amdgcn_exp2f(S0[4 * g + 3]);
            l += (p0 + p1) + (p2 + p3);
            bf16x4 pv; pv[0] = (bf16)p0; pv[1] = (bf16)p1; pv[2] = (bf16)p2; pv[3] = (bf16)p3;
            *(bf16x4*)&Pw[ln5 * 72 + 8 * g + 4 * hi] = pv;
        }
#pragma unroll
        for (int g = 0; g < 4; ++g) {
            float p0 = __builtin_amdgcn_exp2f(S1[4 * g + 0]);
            float p1 = __builtin_amdgcn_exp2f(S1[4 * g + 1]);
            float p2 = __builtin_amdgcn_exp2f(S1[4 * g + 2]);
            float p3 = __builtin_amdgcn_exp2f(S1[4 * g + 3]);
            l += (p0 + p1) + (p2 + p3);
            bf16x4 pv; pv[0] = (bf16)p0; pv[1] = (bf16)p1; pv[2] = (bf16)p2; pv[3] = (bf16)p3;
            *(bf16x4*)&Pw[ln5 * 72 + 32 + 8 * g + 4 * hi] = pv;
        }

        // O^T += V^T * P^T  (k = wave's 64 kr)
#pragma unroll
        for (int ks = 0; ks < 4; ++ks) {
            int j = ((ks * 2 + hi) ^ swz) * 8;
            bf16x8 bp = *(const bf16x8*)&Pw[ln5 * 72 + ks * 16 + hi * 8];
            bf16x8 v0 = *(const bf16x8*)&KV[vrow0 + j];
            bf16x8 v1 = *(const bf16x8*)&KV[vrow1 + j];
            O0 = MFMA(v0, bp, O0);
            O1 = MFMA(v1, bp, O1);
        }
    }

    l += __shfl_xor(l, 32, 64);
    __syncthreads();                               // k-loop reads done before overlay

    float* Ox = (float*)&KV[0];                    // 16 KB overlay on K region
    if (wk == 1) {
#pragma unroll
        for (int r = 0; r < 16; ++r) Ox[(wq * 32 + r) * 64 + lane] = O0[r];
#pragma unroll
        for (int r = 0; r < 16; ++r) Ox[(wq * 32 + 16 + r) * 64 + lane] = O1[r];
        Lx[wq * 64 + lane] = l;
    }
    __syncthreads();
    if (wk == 0) {
#pragma unroll
        for (int r = 0; r < 16; ++r) O0[r] += Ox[(wq * 32 + r) * 64 + lane];
#pragma unroll
        for (int r = 0; r < 16; ++r) O1[r] += Ox[(wq * 32 + 16 + r) * 64 + lane];
        l += Lx[wq * 64 + lane];
        if (split == 1) {
            float inv = 1.0f / l;
#pragma unroll
            for (int g = 0; g < 4; ++g) {
                float4 o;
                o.x = O0[4*g+0] * inv; o.y = O0[4*g+1] * inv;
                o.z = O0[4*g+2] * inv; o.w = O0[4*g+3] * inv;
                *(float4*)(out + (size_t)qrow * HS + 8 * g + 4 * hi) = o;
            }
#pragma unroll
            for (int g = 0; g < 4; ++g) {
                float4 o;
                o.x = O1[4*g+0] * inv; o.y = O1[4*g+1] * inv;
                o.z = O1[4*g+2] * inv; o.w = O1[4*g+3] * inv;
                *(float4*)(out + (size_t)qrow * HS + 32 + 8 * g + 4 * hi) = o;
            }
        } else {
            float* Od = Op + (size_t)half * ROWS * HS + (size_t)qrow * HS;
#pragma unroll
            for (int g = 0; g < 4; ++g) {
                float4 o;
                o.x = O0[4*g+0]; o.y = O0[4*g+1]; o.z = O0[4*g+2]; o.w = O0[4*g+3];
                *(float4*)(Od + 8 * g + 4 * hi) = o;
            }
#pragma unroll
            for (int g = 0; g < 4; ++g) {
                float4 o;
                o.x = O1[4*g+0]; o.y = O1[4*g+1]; o.z = O1[4*g+2]; o.w = O1[4*g+3];
                *(float4*)(Od + 32 + 8 * g + 4 * hi) = o;
            }
            if (hi == 0) Lp[half * ROWS + qrow] = l;
        }
    }
}

// ---- reduce: out = sum_h(O_h) / sum_h(l_h) ----
__global__ __launch_bounds__(256) void attn_reduce(
    const float* __restrict__ Op, const float* __restrict__ Lp,
    float* __restrict__ out, int split)
{
    int idx = blockIdx.x * 256 + threadIdx.x;      // float4 index
    int row = idx >> 4;
    float4 s; s.x = s.y = s.z = s.w = 0.f;
    float lsum = 0.f;
    for (int h = 0; h < split; ++h) {
        float4 a = *(const float4*)(Op + (size_t)h * ROWS * HS + (size_t)idx * 4);
        s.x += a.x; s.y += a.y; s.z += a.z; s.w += a.w;
        lsum += Lp[h * ROWS + row];
    }
    float inv = 1.0f / lsum;
    s.x *= inv; s.y *= inv; s.z *= inv; s.w *= inv;
    *(float4*)(out + (size_t)idx * 4) = s;
}

extern "C" void kernel_launch(void* const* d_in, const int* in_sizes, int n_in,
                              void* d_out, int out_size, void* d_ws, size_t ws_size,
                              hipStream_t stream)
{
    const float* x  = (const float*)d_in[0];
    const float* Wq = (const float*)d_in[1];
    const float* Wk = (const float*)d_in[2];
    const float* Wv = (const float*)d_in[3];
    float* out = (float*)d_out;

    char* ws = (char*)d_ws;
    bf16* Qg  = (bf16*)(ws);                          // 2 MB  [16384][64]
    bf16* Kgt = (bf16*)(ws + ((size_t)2 << 20));      // 2 MB  tiled+swizzled
    bf16* Vgt = (bf16*)(ws + ((size_t)4 << 20));      // 2 MB  tiled+swizzled
    bf16* Wt  = (bf16*)(ws + ((size_t)6 << 20));      // 384 KB [192][1024]
    float* Lp = (float*)(ws + ((size_t)6 << 20));     // overlays Wt (dead after proj)
    float* Op = (float*)(ws + ((size_t)6 << 20) + ((size_t)1 << 19));

    const size_t base = ((size_t)6 << 20) + ((size_t)1 << 19);
    int split = 1;
    if (ws_size >= base + (size_t)4 * ROWS * HS * sizeof(float)) split = 4;
    else if (ws_size >= base + (size_t)2 * ROWS * HS * sizeof(float)) split = 2;

    prep_wt<<<48, 256, 0, stream>>>(Wq, Wk, Wv, Wt);
    qkv_proj<<<ROWS / 64, 256, 0, stream>>>(x, Wt, Qg, Kgt, Vgt);
    attn<<<256 * split, 256, 0, stream>>>(Qg, Kgt, Vgt, Op, Lp, out, split);
    if (split > 1)
        attn_reduce<<<(ROWS * HS / 4) / 256, 256, 0, stream>>>(Op, Lp, out, split);
}

// Round 8
// 150.693 us; speedup vs baseline: 1.6719x; 1.0230x over previous
//
#include <hip/hip_runtime.h>

// Round 8: ping-pong LDS double-buffering + 2x arithmetic intensity.
//  - attn: wave = 64 q-cols (Q frags in regs) x wk half of each 64-kr chunk.
//    Ping-pong KV buffers: stage(c+1) issued before compute(c) so the barrier
//    vmcnt drain is covered by compute. One barrier per chunk.
//  - proj: grid 768 (Q/K/V block per 64-row tile, XCD-pinned), ping-pong
//    x(fp32)+W staging, 3 blocks/CU.
//  - K/V kept tiled+swizzled in global (linear global_load_lds staging).

typedef __bf16 bf16;
typedef __bf16 bf16x4 __attribute__((ext_vector_type(4)));
typedef __bf16 bf16x8 __attribute__((ext_vector_type(8)));
typedef float  f32x16 __attribute__((ext_vector_type(16)));

#define MFMA(a, b, c) __builtin_amdgcn_mfma_f32_32x32x16_bf16(a, b, c, 0, 0, 0)

constexpr int T = 4096, D = 1024, HS = 64;
constexpr int ROWS = 4 * T;                   // 16384
constexpr float QSCL = 0.045084220027797f;    // (1/32) * log2(e)

__device__ __forceinline__ void gld16(const void* g, void* l) {
    __builtin_amdgcn_global_load_lds(
        (const __attribute__((address_space(1))) unsigned int*)g,
        (__attribute__((address_space(3))) unsigned int*)l, 16, 0, 0);
}

__device__ inline f32x16 zero16() {
    f32x16 z;
#pragma unroll
    for (int i = 0; i < 16; ++i) z[i] = 0.f;
    return z;
}

// ---- prep: Wt[192][1024] bf16 = concat(Wq^T*QSCL, Wk^T, Wv^T) ----
__global__ __launch_bounds__(256) void prep_wt(
    const float* __restrict__ Wq, const float* __restrict__ Wk,
    const float* __restrict__ Wv, bf16* __restrict__ Wt)
{
    __shared__ float Xf[64 * 68];
    const int m = blockIdx.x >> 4, dt = blockIdx.x & 15;
    const float* W = (m == 0) ? Wq : ((m == 1) ? Wk : Wv);
    const int d0 = dt * 64;
#pragma unroll
    for (int j = 0; j < 4; ++j) {
        int i = threadIdx.x + 256 * j;
        int dr = i >> 4, c4 = i & 15;
        float4 v = *(const float4*)(W + (size_t)(d0 + dr) * 64 + c4 * 4);
        *(float4*)&Xf[dr * 68 + c4 * 4] = v;
    }
    __syncthreads();
    const float scl = (m == 0) ? QSCL : 1.0f;
#pragma unroll
    for (int j = 0; j < 4; ++j) {
        int o = threadIdx.x + 256 * j;
        int h = o >> 4, dc = o & 15;
        bf16x4 w;
#pragma unroll
        for (int k = 0; k < 4; ++k) w[k] = (bf16)(Xf[(dc * 4 + k) * 68 + h] * scl);
        *(bf16x4*)(Wt + (size_t)(m * 64 + h) * D + d0 + dc * 4) = w;
    }
}

// ---- projection: grid 768 = 8 xcd x 32 mtile x 3 which; ping-pong dbuf ----
__global__ __launch_bounds__(256, 3) void qkv_proj(
    const float* __restrict__ x, const bf16* __restrict__ Wt,
    bf16* __restrict__ Qg, bf16* __restrict__ Kgt, bf16* __restrict__ Vgt)
{
    __shared__ __align__(16) float Xs[2][64 * 64];   // swizzled: [r][u^(r&15)]
    __shared__ __align__(16) short Ws[2][64 * 64];   // swizzled: [h][u^(h&7)]
    const int tid = threadIdx.x;
    const int w = tid >> 6, lane = tid & 63, ln5 = lane & 31, hi = lane >> 5;
    const int tt = w & 1, hh = w >> 1;
    const int xcd = blockIdx.x & 7, t3 = blockIdx.x >> 3;
    const int which = t3 % 3, mlocal = t3 / 3;       // same x-tile -> same xcd
    const int r0 = (xcd * 32 + mlocal) * 64;
    const int wb = tid & 448;

    auto stage = [&](int kc, int buf) {
#pragma unroll
        for (int k2 = 0; k2 < 4; ++k2) {             // x tile 16 KB fp32
            int s = k2 * 256 + tid;
            int r = s >> 4, j = s & 15, u = j ^ (r & 15);
            gld16(x + (size_t)(r0 + r) * D + kc * 64 + u * 4,
                  &Xs[buf][(k2 * 256 + wb) * 4]);
        }
#pragma unroll
        for (int k2 = 0; k2 < 2; ++k2) {             // W slice 8 KB bf16
            int s = k2 * 256 + tid;
            int h = s >> 3, j = s & 7, u = j ^ (h & 7);
            gld16(Wt + (size_t)(which * 64 + h) * D + kc * 64 + u * 8,
                  &Ws[buf][(k2 * 256 + wb) * 8]);
        }
    };

    f32x16 acc = zero16();
    const int rx = tt * 32 + ln5;
    const int hq = hh * 32 + ln5;
    const int swz = ln5 & 7;

    stage(0, 0);
    __syncthreads();
    for (int kc = 0; kc < 16; ++kc) {
        const int cur = kc & 1;
        if (kc < 15) stage(kc + 1, cur ^ 1);
        const float* Xb = &Xs[cur][0];
        const short* Wb = &Ws[cur][0];
#pragma unroll
        for (int ks = 0; ks < 4; ++ks) {
            int u0 = ks * 4 + hi * 2;
            float4 a = *(const float4*)&Xb[rx * 64 + ((u0)     ^ (rx & 15)) * 4];
            float4 b = *(const float4*)&Xb[rx * 64 + ((u0 + 1) ^ (rx & 15)) * 4];
            bf16x8 fx;
            fx[0] = (bf16)a.x; fx[1] = (bf16)a.y; fx[2] = (bf16)a.z; fx[3] = (bf16)a.w;
            fx[4] = (bf16)b.x; fx[5] = (bf16)b.y; fx[6] = (bf16)b.z; fx[7] = (bf16)b.w;
            bf16x8 wf = *(const bf16x8*)&Wb[hq * 64 + (((ks * 2 + hi) ^ swz) * 8)];
            if (which < 2) acc = MFMA(wf, fx, acc);   // C^T (col = t)
            else           acc = MFMA(fx, wf, acc);   // C   (col = h)
        }
        __syncthreads();
    }

    if (which < 2) {
        int t = r0 + tt * 32 + ln5;
#pragma unroll
        for (int g = 0; g < 4; ++g) {
            int h0 = hh * 32 + 8 * g + 4 * hi;
            bf16x4 v;
#pragma unroll
            for (int k = 0; k < 4; ++k) v[k] = (bf16)acc[4 * g + k];
            if (which == 0) {
                *(bf16x4*)(Qg + (size_t)t * HS + h0) = v;
            } else {
                int j = (h0 >> 3) ^ (t & 7);
                *(bf16x4*)(Kgt + (size_t)t * HS + j * 8 + 4 * hi) = v;
            }
        }
    } else {
        int hr = hh * 32 + ln5;
#pragma unroll
        for (int g = 0; g < 4; ++g) {
            int t0 = tt * 32 + 8 * g + 4 * hi;
            bf16x4 v;
#pragma unroll
            for (int k = 0; k < 4; ++k) v[k] = (bf16)acc[4 * g + k];
            int j = (t0 >> 3) ^ (hr & 7);
            *(bf16x4*)(Vgt + (size_t)r0 * HS + hr * 64 + j * 8 + 4 * hi) = v;
        }
    }
}

// ---- attention: block = 128 q-rows; wave = 64 q-cols x 32-kr half-chunk ----
__global__ __launch_bounds__(256, 2) void attn(
    const bf16* __restrict__ Qg, const bf16* __restrict__ Kgt,
    const bf16* __restrict__ Vgt, float* __restrict__ Op,
    float* __restrict__ Lp, float* __restrict__ out, int split)
{
    __shared__ __align__(16) short KV[2][8192];      // buf: K [0,4096) V [4096,8192) shorts
    __shared__ __align__(16) short Ps[4][64 * 40];   // per-wave P^T: [q 64][kr 32] +pad
    __shared__ float Lx[128];

    const int tid = threadIdx.x;
    const int w = tid >> 6, lane = tid & 63, ln5 = lane & 31, hi = lane >> 5;
    const int wq = w & 1, wk = w >> 1;
    const int wb = tid & 448;

    int b, qt, half;
    if (split == 4) {
        int rest = blockIdx.x >> 3; qt = rest & 31;
        int combo = (blockIdx.x & 7) + 8 * (rest >> 5);   // (b,half) pinned per XCD
        b = combo >> 2; half = combo & 3;
    } else if (split == 2) {
        int c2 = blockIdx.x & 7; b = c2 >> 1; half = c2 & 1; qt = blockIdx.x >> 3;
    } else { b = blockIdx.x & 3; half = 0; qt = blockIdx.x >> 2; }

    const int rbase = b * T;
    const int seg = T / split;
    const int kb0 = rbase + half * seg;
    const int nc = seg / 64;
    const int qrow0 = rbase + qt * 128 + wq * 64;

    // Q B-frags: 64 q-cols held in registers for the whole k-loop
    bf16x8 bq[2][4];
    {
        const bf16* qp = Qg + (size_t)(qrow0 + ln5) * HS + hi * 8;
#pragma unroll
        for (int qs = 0; qs < 2; ++qs)
#pragma unroll
            for (int ks = 0; ks < 4; ++ks)
                bq[qs][ks] = *(const bf16x8*)(qp + (size_t)qs * 32 * HS + ks * 16);
    }

    const bf16* Kc = Kgt + (size_t)kb0 * HS;
    const bf16* Vc = Vgt + (size_t)kb0 * HS;
    auto stage = [&](int c, int buf) {
#pragma unroll
        for (int k2 = 0; k2 < 2; ++k2) {
            int s = k2 * 256 + tid;
            gld16(Kc + (size_t)c * 4096 + s * 8, &KV[buf][(k2 * 256 + wb) * 8]);
            gld16(Vc + (size_t)c * 4096 + s * 8, &KV[buf][4096 + (k2 * 256 + wb) * 8]);
        }
    };

    f32x16 O00 = zero16(), O01 = zero16(), O10 = zero16(), O11 = zero16();
    float l0 = 0.f, l1 = 0.f;
    short* Pw = &Ps[w][0];
    const int swz = ln5 & 7;
    const int krow = (wk * 32 + ln5) * 64;           // K frag row (shorts)

    stage(0, 0);
    __syncthreads();

    for (int c = 0; c < nc; ++c) {
        const int cur = c & 1;
        if (c + 1 < nc) stage(c + 1, cur ^ 1);       // in-flight across compute
        const short* Kb = &KV[cur][0];
        const short* Vb = &KV[cur][4096];

        // S^T = K_slice * Q^T  (32 kr x 64 q)
        f32x16 S0 = zero16(), S1 = zero16();
#pragma unroll
        for (int ks = 0; ks < 4; ++ks) {
            bf16x8 kf = *(const bf16x8*)&Kb[krow + (((ks * 2 + hi) ^ swz) * 8)];
            S0 = MFMA(kf, bq[0][ks], S0);
            S1 = MFMA(kf, bq[1][ks], S1);
        }

        // no-max softmax; P^T (bf16) q-major into per-wave LDS
#pragma unroll
        for (int g = 0; g < 4; ++g) {
            float p0 = __builtin_amdgcn_exp2f(S0[4 * g + 0]);
            float p1 = __builtin_amdgcn_exp2f(S0[4 * g + 1]);
            float p2 = __builtin_amdgcn_exp2f(S0[4 * g + 2]);
            float p3 = __builtin_amdgcn_exp2f(S0[4 * g + 3]);
            l0 += (p0 + p1) + (p2 + p3);
            bf16x4 pv; pv[0] = (bf16)p0; pv[1] = (bf16)p1; pv[2] = (bf16)p2; pv[3] = (bf16)p3;
            *(bf16x4*)&Pw[ln5 * 40 + 8 * g + 4 * hi] = pv;
        }
#pragma unroll
        for (int g = 0; g < 4; ++g) {
            float p0 = __builtin_amdgcn_exp2f(S1[4 * g + 0]);
            float p1 = __builtin_amdgcn_exp2f(S1[4 * g + 1]);
            float p2 = __builtin_amdgcn_exp2f(S1[4 * g + 2]);
            float p3 = __builtin_amdgcn_exp2f(S1[4 * g + 3]);
            l1 += (p0 + p1) + (p2 + p3);
            bf16x4 pv; pv[0] = (bf16)p0; pv[1] = (bf16)p1; pv[2] = (bf16)p2; pv[3] = (bf16)p3;
            *(bf16x4*)&Pw[(32 + ln5) * 40 + 8 * g + 4 * hi] = pv;
        }

        // O^T += V^T_slice * P^T  (k = wave's 32 kr; kr-local indexing in P)
#pragma unroll
        for (int ks = 0; ks < 2; ++ks) {
            int ku = (wk * 4 + ks * 2 + hi) ^ swz;   // global kr unit, swizzled
            bf16x8 pf0 = *(const bf16x8*)&Pw[ln5 * 40 + ks * 16 + hi * 8];
            bf16x8 pf1 = *(const bf16x8*)&Pw[(32 + ln5) * 40 + ks * 16 + hi * 8];
            bf16x8 vf0 = *(const bf16x8*)&Vb[ln5 * 64 + ku * 8];
            bf16x8 vf1 = *(const bf16x8*)&Vb[(32 + ln5) * 64 + ku * 8];
            O00 = MFMA(vf0, pf0, O00);
            O01 = MFMA(vf0, pf1, O01);
            O10 = MFMA(vf1, pf0, O10);
            O11 = MFMA(vf1, pf1, O11);
        }
        __syncthreads();                             // drains stage(c+1); buf reuse safe
    }

    l0 += __shfl_xor(l0, 32, 64);
    l1 += __shfl_xor(l1, 32, 64);

    // wk-combine through 32 KB Ox overlay on KV
    float* Ox = (float*)&KV[0][0];                   // [wq][h 64][q 64]
    if (wk == 1) {
#pragma unroll
        for (int g = 0; g < 4; ++g)
#pragma unroll
            for (int k = 0; k < 4; ++k) {
                int h0 = 8 * g + 4 * hi + k;
                Ox[wq * 4096 + h0 * 64 + ln5]             = O00[4 * g + k];
                Ox[wq * 4096 + h0 * 64 + 32 + ln5]        = O01[4 * g + k];
                Ox[wq * 4096 + (32 + h0) * 64 + ln5]      = O10[4 * g + k];
                Ox[wq * 4096 + (32 + h0) * 64 + 32 + ln5] = O11[4 * g + k];
            }
        if (hi == 0) { Lx[wq * 64 + ln5] = l0; Lx[wq * 64 + 32 + ln5] = l1; }
    }
    __syncthreads();
    if (wk == 0) {
#pragma unroll
        for (int g = 0; g < 4; ++g)
#pragma unroll
            for (int k = 0; k < 4; ++k) {
                int h0 = 8 * g + 4 * hi + k;
                O00[4 * g + k] += Ox[wq * 4096 + h0 * 64 + ln5];
                O01[4 * g + k] += Ox[wq * 4096 + h0 * 64 + 32 + ln5];
                O10[4 * g + k] += Ox[wq * 4096 + (32 + h0) * 64 + ln5];
                O11[4 * g + k] += Ox[wq * 4096 + (32 + h0) * 64 + 32 + ln5];
            }
        l0 += Lx[wq * 64 + ln5];
        l1 += Lx[wq * 64 + 32 + ln5];

        int q0 = qrow0 + ln5, q1 = qrow0 + 32 + ln5;
        if (split == 1) {
            float i0 = 1.0f / l0, i1 = 1.0f / l1;
#pragma unroll
            for (int g = 0; g < 4; ++g) {
                int h0 = 8 * g + 4 * hi;
                float4 o;
                o.x = O00[4*g+0]*i0; o.y = O00[4*g+1]*i0; o.z = O00[4*g+2]*i0; o.w = O00[4*g+3]*i0;
                *(float4*)(out + (size_t)q0 * HS + h0) = o;
                o.x = O01[4*g+0]*i1; o.y = O01[4*g+1]*i1; o.z = O01[4*g+2]*i1; o.w = O01[4*g+3]*i1;
                *(float4*)(out + (size_t)q1 * HS + h0) = o;
                o.x = O10[4*g+0]*i0; o.y = O10[4*g+1]*i0; o.z = O10[4*g+2]*i0; o.w = O10[4*g+3]*i0;
                *(float4*)(out + (size_t)q0 * HS + 32 + h0) = o;
                o.x = O11[4*g+0]*i1; o.y = O11[4*g+1]*i1; o.z = O11[4*g+2]*i1; o.w = O11[4*g+3]*i1;
                *(float4*)(out + (size_t)q1 * HS + 32 + h0) = o;
            }
        } else {
            float* Od = Op + (size_t)half * ROWS * HS;
#pragma unroll
            for (int g = 0; g < 4; ++g) {
                int h0 = 8 * g + 4 * hi;
                float4 o;
                o.x = O00[4*g+0]; o.y = O00[4*g+1]; o.z = O00[4*g+2]; o.w = O00[4*g+3];
                *(float4*)(Od + (size_t)q0 * HS + h0) = o;
                o.x = O01[4*g+0]; o.y = O01[4*g+1]; o.z = O01[4*g+2]; o.w = O01[4*g+3];
                *(float4*)(Od + (size_t)q1 * HS + h0) = o;
                o.x = O10[4*g+0]; o.y = O10[4*g+1]; o.z = O10[4*g+2]; o.w = O10[4*g+3];
                *(float4*)(Od + (size_t)q0 * HS + 32 + h0) = o;
                o.x = O11[4*g+0]; o.y = O11[4*g+1]; o.z = O11[4*g+2]; o.w = O11[4*g+3];
                *(float4*)(Od + (size_t)q1 * HS + 32 + h0) = o;
            }
            if (hi == 0) {
                Lp[half * ROWS + q0] = l0;
                Lp[half * ROWS + q1] = l1;
            }
        }
    }
}

// ---- reduce: out = sum_h(O_h) / sum_h(l_h) ----
__global__ __launch_bounds__(256) void attn_reduce(
    const float* __restrict__ Op, const float* __restrict__ Lp,
    float* __restrict__ out, int split)
{
    int idx = blockIdx.x * 256 + threadIdx.x;        // float4 index
    int row = idx >> 4;
    float4 s; s.x = s.y = s.z = s.w = 0.f;
    float lsum = 0.f;
    for (int h = 0; h < split; ++h) {
        float4 a = *(const float4*)(Op + (size_t)h * ROWS * HS + (size_t)idx * 4);
        s.x += a.x; s.y += a.y; s.z += a.z; s.w += a.w;
        lsum += Lp[h * ROWS + row];
    }
    float inv = 1.0f / lsum;
    s.x *= inv; s.y *= inv; s.z *= inv; s.w *= inv;
    *(float4*)(out + (size_t)idx * 4) = s;
}

extern "C" void kernel_launch(void* const* d_in, const int* in_sizes, int n_in,
                              void* d_out, int out_size, void* d_ws, size_t ws_size,
                              hipStream_t stream)
{
    const float* x  = (const float*)d_in[0];
    const float* Wq = (const float*)d_in[1];
    const float* Wk = (const float*)d_in[2];
    const float* Wv = (const float*)d_in[3];
    float* out = (float*)d_out;

    char* ws = (char*)d_ws;
    bf16* Qg  = (bf16*)(ws);                          // 2 MB  [16384][64]
    bf16* Kgt = (bf16*)(ws + ((size_t)2 << 20));      // 2 MB  tiled+swizzled
    bf16* Vgt = (bf16*)(ws + ((size_t)4 << 20));      // 2 MB  tiled+swizzled
    bf16* Wt  = (bf16*)(ws + ((size_t)6 << 20));      // 384 KB [192][1024]
    float* Lp = (float*)(ws + ((size_t)6 << 20));     // overlays Wt (dead after proj)
    float* Op = (float*)(ws + ((size_t)6 << 20) + ((size_t)1 << 19));

    const size_t base = ((size_t)6 << 20) + ((size_t)1 << 19);
    int split = 1;
    if (ws_size >= base + (size_t)4 * ROWS * HS * sizeof(float)) split = 4;
    else if (ws_size >= base + (size_t)2 * ROWS * HS * sizeof(float)) split = 2;

    prep_wt<<<48, 256, 0, stream>>>(Wq, Wk, Wv, Wt);
    qkv_proj<<<768, 256, 0, stream>>>(x, Wt, Qg, Kgt, Vgt);
    attn<<<128 * split, 256, 0, stream>>>(Qg, Kgt, Vgt, Op, Lp, out, split);
    if (split > 1)
        attn_reduce<<<(ROWS * HS / 4) / 256, 256, 0, stream>>>(Op, Lp, out, split);
}